// Round 6
// baseline (137.251 us; speedup 1.0000x reference)
//
#include <hip/hip_runtime.h>
#include <hip/hip_bf16.h>
#include <math.h>

#define BSZ 4096
#define D 128
#define NCLS 64
#define MARGIN_F 1.0f
#define LOSS_BLOCKS 256

typedef short bf16x8 __attribute__((ext_vector_type(8)));
typedef float f32x4  __attribute__((ext_vector_type(4)));

// ---- all scratch in device globals: no d_ws usage, graph-safe, re-inited every call ----
__device__ float g_row_neg[BSZ];
__device__ float g_acc;
__device__ int   g_hist[NCLS];
__device__ int   g_offs[NCLS];
__device__ int   g_counter;
__device__ int   g_order[BSZ];
__device__ int   g_done;

__device__ __forceinline__ unsigned short f2bf(float x) {
    union { __hip_bfloat16 h; unsigned short u; } cv;
    cv.h = __float2bfloat16(x);     // HW RNE convert (compiler emits v_cvt)
    return cv.u;
}

// ---------------- prep: zero accumulators + hist + scan + scatter (1 block) ----------------
__global__ __launch_bounds__(1024) void prep_kernel(const int* __restrict__ T) {
    __shared__ int hw[16][NCLS];    // per-wave histograms: no same-address contention across waves
    __shared__ int cur[NCLS];
    const int tid = threadIdx.x;
    const int w = tid >> 6;
#pragma unroll
    for (int j = 0; j < 4; ++j) g_row_neg[tid + j * 1024] = 0.0f;
    if (tid == 0) { g_acc = 0.0f; g_done = 0; }
    hw[tid >> 6][tid & 63] = 0;     // 16*64 == 1024: one slot per thread
    __syncthreads();
    int lab[4];
#pragma unroll
    for (int j = 0; j < 4; ++j) lab[j] = T[tid + j * 1024];
#pragma unroll
    for (int j = 0; j < 4; ++j) atomicAdd(&hw[w][lab[j]], 1);
    __syncthreads();
    if (tid < 64) {                 // wave 0: combine + scan + pair counter
        int n = 0;
#pragma unroll
        for (int w2 = 0; w2 < 16; ++w2) n += hw[w2][tid];
        int x = n;
#pragma unroll
        for (int off = 1; off < 64; off <<= 1) {
            int y = __shfl_up(x, off);
            if (tid >= off) x += y;
        }
        g_offs[tid] = x - n; g_hist[tid] = n; cur[tid] = x - n;
        int pc = n * (n - 1) / 2;
#pragma unroll
        for (int off = 32; off > 0; off >>= 1) pc += __shfl_down(pc, off);
        if (tid == 0) g_counter = pc;
    }
    __syncthreads();
#pragma unroll
    for (int j = 0; j < 4; ++j) {
        int p = atomicAdd(&cur[lab[j]], 1);
        g_order[p] = tid + j * 1024;
    }
}

// ---------------- row_neg: bf16 MFMA symmetric tiled Gram + masked exp row/col sums ----------
// Grid = 2080 upper-triangle blocks; (bi,bj) decoded from linear id. 64x64 tile per block via
// mfma_f32_16x16x32_bf16 (4 waves x 2x2 frags). LDS tiles bf16 row-major [64][128] with
// 16B-chunk XOR swizzle (chunk ^ (row&7)) -> conflict-free ds_read_b128 fragments.
// A/B fragments use IDENTICAL lane patterns so any k-permutation cancels in A*A^T.
// C/D layout: col=lane&15, row=(lane>>4)*4+reg (m89-verified; validated on-HW round 5).
// f32 mags are safe: only label-masked (same-label) entries can have d2~0, so bf16/f32
// consistency at the sqrt clamp is irrelevant.
__global__ __launch_bounds__(256) void rowneg_kernel(const float* __restrict__ X,
                                                     const int* __restrict__ T) {
    // triangular decode: cum(r) = r*(129-r)/2 (exact in int)
    const int p = blockIdx.x;
    int bi = (int)((129.0f - sqrtf(16641.0f - 8.0f * (float)p)) * 0.5f);
    bi = max(0, min(63, bi));
    while (bi * (129 - bi) / 2 > p) --bi;
    while (bi < 63 && (bi + 1) * (129 - (bi + 1)) / 2 <= p) ++bi;
    const int bj = bi + (p - bi * (129 - bi) / 2);

    __shared__ __align__(16) unsigned short Ab[64 * 128];  // 16 KB
    __shared__ __align__(16) unsigned short Bb[64 * 128];  // 16 KB
    __shared__ float magA[64], magB[64];
    __shared__ int   labA[64], labB[64];

    const int tid = threadIdx.x;
    const int biBase = bi * 64, bjBase = bj * 64;

    // ---- stage A,B tiles + fused f32 mags: thread t owns row t>>2, quarter t&3 ----
    {
        const int srow = tid >> 2, part = tid & 3;
        const float4* GA = (const float4*)(X + (size_t)(biBase + srow) * D) + part * 8;
        const float4* GB = (const float4*)(X + (size_t)(bjBase + srow) * D) + part * 8;
        float ma = 0.0f, mb = 0.0f;
#pragma unroll
        for (int k = 0; k < 8; ++k) {
            int f = part * 8 + k;
            int byteoff = srow * 256 + (((f >> 1) ^ (srow & 7)) << 4) + ((f & 1) << 3);
            float4 a = GA[k];
            ma = fmaf(a.x, a.x, fmaf(a.y, a.y, fmaf(a.z, a.z, fmaf(a.w, a.w, ma))));
            *(ushort4*)((char*)Ab + byteoff) = make_ushort4(f2bf(a.x), f2bf(a.y), f2bf(a.z), f2bf(a.w));
            float4 b = GB[k];
            mb = fmaf(b.x, b.x, fmaf(b.y, b.y, fmaf(b.z, b.z, fmaf(b.w, b.w, mb))));
            *(ushort4*)((char*)Bb + byteoff) = make_ushort4(f2bf(b.x), f2bf(b.y), f2bf(b.z), f2bf(b.w));
        }
        ma += __shfl_xor(ma, 1); ma += __shfl_xor(ma, 2);   // reduce 4 quarter-row lanes
        mb += __shfl_xor(mb, 1); mb += __shfl_xor(mb, 2);
        if (part == 0) { magA[srow] = ma; magB[srow] = mb; }
    }
    if (tid >= 128 && tid < 192) labA[tid - 128] = T[biBase + tid - 128];
    if (tid >= 192)              labB[tid - 192] = T[bjBase + tid - 192];
    __syncthreads();

    // ---- MFMA: each wave computes a 32x32 quadrant (2x2 fragments), K=128 in 4 steps ----
    const int l = tid & 63, w = tid >> 6;
    const int wr = w >> 1, wc = w & 1;
    const int l15 = l & 15, l4 = l >> 4;

    f32x4 acc[2][2];
#pragma unroll
    for (int mi = 0; mi < 2; ++mi)
#pragma unroll
        for (int ni = 0; ni < 2; ++ni)
            acc[mi][ni] = (f32x4){0.0f, 0.0f, 0.0f, 0.0f};

#pragma unroll
    for (int ks = 0; ks < 4; ++ks) {
        int cch = ks * 4 + l4;                  // 16B chunk index = k-offset/8
        bf16x8 afr[2], bfr[2];
#pragma unroll
        for (int mi = 0; mi < 2; ++mi) {
            int row = wr * 32 + mi * 16 + l15;
            afr[mi] = *(const bf16x8*)((const char*)Ab + row * 256 + ((cch ^ (row & 7)) << 4));
        }
#pragma unroll
        for (int ni = 0; ni < 2; ++ni) {
            int row = wc * 32 + ni * 16 + l15;
            bfr[ni] = *(const bf16x8*)((const char*)Bb + row * 256 + ((cch ^ (row & 7)) << 4));
        }
#pragma unroll
        for (int mi = 0; mi < 2; ++mi)
#pragma unroll
            for (int ni = 0; ni < 2; ++ni)
                acc[mi][ni] = __builtin_amdgcn_mfma_f32_16x16x32_bf16(
                    afr[mi], bfr[ni], acc[mi][ni], 0, 0, 0);
    }

    // ---- epilogue: masked exp; shuffle-reduced row/col sums -> direct global atomics ----
    float rp[2][4] = {{0.f,0.f,0.f,0.f},{0.f,0.f,0.f,0.f}};
    float cp[2] = {0.f, 0.f};
#pragma unroll
    for (int mi = 0; mi < 2; ++mi)
#pragma unroll
        for (int ni = 0; ni < 2; ++ni)
#pragma unroll
            for (int j = 0; j < 4; ++j) {
                int rl = wr * 32 + mi * 16 + l4 * 4 + j;   // local row
                int cl = wc * 32 + ni * 16 + l15;          // local col
                float s = acc[mi][ni][j];
                if (labA[rl] != labB[cl]) {
                    float d2 = fmaxf(magA[rl] + magB[cl] - 2.0f * s, 0.0f);
                    float t = __expf(MARGIN_F - sqrtf(d2));
                    rp[mi][j] += t;
                    cp[ni] += t;
                }
            }

    // row sums: butterfly over the 16 l15 lanes of each group
#pragma unroll
    for (int mi = 0; mi < 2; ++mi)
#pragma unroll
        for (int j = 0; j < 4; ++j) {
            float v = rp[mi][j];
            v += __shfl_xor(v, 1); v += __shfl_xor(v, 2);
            v += __shfl_xor(v, 4); v += __shfl_xor(v, 8);
            rp[mi][j] = v;
        }
    if (l15 == 0) {
#pragma unroll
        for (int mi = 0; mi < 2; ++mi)
#pragma unroll
            for (int j = 0; j < 4; ++j)
                atomicAdd(&g_row_neg[biBase + wr * 32 + mi * 16 + l4 * 4 + j], rp[mi][j]);
    }
    // col sums (symmetric contribution): butterfly over the 4 l4 groups
    if (bj > bi) {
#pragma unroll
        for (int ni = 0; ni < 2; ++ni) {
            float v = cp[ni];
            v += __shfl_xor(v, 16); v += __shfl_xor(v, 32);
            if (l4 == 0)
                atomicAdd(&g_row_neg[bjBase + wc * 32 + ni * 16 + l15], v);
        }
    }
}

// ---------------- positive-pair hinge loss + fused final division ----------------
__global__ __launch_bounds__(256) void loss_kernel(const float* __restrict__ X,
                                                   float* __restrict__ out) {
    const int c = blockIdx.x;
    const int n = g_hist[c];
    const int base = g_offs[c];
    const long long P = (long long)n * (n - 1) / 2;
    float lacc = 0.0f;

    for (long long p = threadIdx.x + (long long)blockIdx.y * 256; p < P; p += 1024) {
        // decode (a,b), a<b, from linear upper-triangular index p
        float nf = (float)n;
        float pf = (float)p;
        int a = (int)((nf - 0.5f) - sqrtf((nf - 0.5f) * (nf - 0.5f) - 2.0f * pf));
        if (a < 0) a = 0;
        if (a > n - 2) a = n - 2;
        auto cum = [&](int aa) -> long long {
            return (long long)aa * (n - 1) - (long long)aa * (aa - 1) / 2;
        };
        while (cum(a + 1) <= p) ++a;
        while (cum(a) > p) --a;
        int b = (int)(p - cum(a)) + a + 1;

        int ia = g_order[base + a], ib = g_order[base + b];
        const float4* xa = (const float4*)(X + (size_t)ia * D);
        const float4* xb = (const float4*)(X + (size_t)ib * D);
        float d2 = 0.0f;
#pragma unroll
        for (int k = 0; k < D / 4; ++k) {
            float4 u = xa[k]; float4 v = xb[k];
            float dx = u.x - v.x, dy = u.y - v.y, dz = u.z - v.z, dw = u.w - v.w;
            d2 = fmaf(dx, dx, d2); d2 = fmaf(dy, dy, d2);
            d2 = fmaf(dz, dz, d2); d2 = fmaf(dw, dw, d2);
        }
        float dist = sqrtf(d2);
        float ln = logf(g_row_neg[ia] + g_row_neg[ib]);
        float h = fmaxf(ln + dist, 0.0f);
        lacc = fmaf(h, h, lacc);
    }

    for (int off = 32; off > 0; off >>= 1) lacc += __shfl_down(lacc, off);
    __shared__ float ws[4];
    int lane = threadIdx.x & 63, w = threadIdx.x >> 6;
    if (lane == 0) ws[w] = lacc;
    __syncthreads();
    if (threadIdx.x == 0) {
        atomicAdd(&g_acc, ws[0] + ws[1] + ws[2] + ws[3]);
        __threadfence();
        int d = atomicAdd(&g_done, 1);
        if (d == LOSS_BLOCKS - 1) {            // last block: fused final division
            __threadfence();
            float total = atomicAdd(&g_acc, 0.0f);   // device-scope coherent read
            out[0] = total / (2.0f * (float)g_counter);
        }
    }
}

extern "C" void kernel_launch(void* const* d_in, const int* in_sizes, int n_in,
                              void* d_out, int out_size, void* d_ws, size_t ws_size,
                              hipStream_t stream) {
    const float* X = (const float*)d_in[0];
    const int* T = (const int*)d_in[1];
    float* out = (float*)d_out;
    (void)d_ws; (void)ws_size;

    prep_kernel<<<dim3(1), dim3(1024), 0, stream>>>(T);
    rowneg_kernel<<<dim3(2080), dim3(256), 0, stream>>>(X, T);
    loss_kernel<<<dim3(64, 4), dim3(256), 0, stream>>>(X, out);
}